// Round 10
// baseline (324.269 us; speedup 1.0000x reference)
//
#include <hip/hip_runtime.h>
#include <hip/hip_bf16.h>
#include <stdint.h>

#define L_SEQ  4096
#define H_DIM  512
#define N_ST   64
#define N_B    8
#define N_CH   16
#define T_CH   256
#define K_GEMM 1024

typedef float  f32x4  __attribute__((ext_vector_type(4)));
typedef __bf16 bf16x8 __attribute__((ext_vector_type(8)));
typedef __bf16 bf16x4 __attribute__((ext_vector_type(4)));
typedef unsigned short u16x8 __attribute__((ext_vector_type(8)));
typedef unsigned long long ull;

#define GLOAD16(g, l) __builtin_amdgcn_global_load_lds( \
    (const __attribute__((address_space(1))) void*)(g), \
    (__attribute__((address_space(3))) void*)(l), 16, 0, 0)

// ---------------- K0: precompute A_bar, C*B_bar, A_bar^T, log2(A_bar) ----------------
__global__ __launch_bounds__(256) void k_precompute(
    const float* __restrict__ A_log, const float* __restrict__ Bv,
    const float* __restrict__ C, const float* __restrict__ log_dt,
    const float* __restrict__ A_log_r, const float* __restrict__ B_r,
    const float* __restrict__ C_r,
    float* __restrict__ pA, float* __restrict__ pCB, float* __restrict__ pPW,
    float* __restrict__ pLG)
{
    int tid = blockIdx.x * 256 + threadIdx.x;      // 2*512*64
    int n   = tid & 63;
    int h   = (tid >> 6) & 511;
    int dir = tid >> 15;
    float dt = expf(log_dt[h]);
    const float* Al = dir ? A_log_r : A_log;
    const float* Bp = dir ? B_r    : Bv;
    const float* Cp = dir ? C_r    : C;
    float eA = expf(Al[h * N_ST + n]);
    float Ab = expf(-dt * eA);
    float Bb = (1.0f - Ab) / eA * Bp[h * N_ST + n];
    pA[tid]  = Ab;
    pCB[tid] = Cp[h * N_ST + n] * Bb;
    pPW[tid] = expf(-dt * eA * (float)T_CH);
    pLG[tid] = -dt * eA * 1.44269504088896f;       // log2(A_bar)
}

// ---------------- Kw: W_bi f32 -> bf16 ----------------
__global__ __launch_bounds__(256) void k_convw(
    const float* __restrict__ W, __bf16* __restrict__ Wbf)
{
    int tid = blockIdx.x * 256 + threadIdx.x;
    Wbf[tid] = (__bf16)W[tid];
}

// ---------------- k_kk: conv kernel taps kk[dirh][d] = sum_n CB_n A_n^d ----------------
__global__ __launch_bounds__(256) void k_kk(
    const float* __restrict__ pCB, const float* __restrict__ pLG,
    float* __restrict__ kk)
{
    __shared__ float scb[64], slg[64];
    int dirh = blockIdx.x;           // 0..1023
    int d = threadIdx.x;             // 0..255
    if (d < 64) { scb[d] = pCB[dirh * 64 + d]; slg[d] = pLG[dirh * 64 + d]; }
    __syncthreads();
    float s = 0.f;
    #pragma unroll
    for (int n = 0; n < 64; ++n) s += scb[n] * exp2f((float)d * slg[n]);
    kk[dirh * 256 + d] = s;
}

// ---------------- k_ut: u [b,l,h] f32 -> ut [h][b][l] bf16 ----------------
__global__ __launch_bounds__(256) void k_ut(
    const float* __restrict__ u, __bf16* __restrict__ ut)
{
    __shared__ float tl[32][65];
    int blk = blockIdx.x;            // 128 l-tiles * 8 h-tiles * 8 b
    int lt = blk & 127, ht = (blk >> 7) & 7, b = blk >> 10;
    int t = threadIdx.x;
    int ho = t & 63, li = t >> 6;
    #pragma unroll
    for (int it = 0; it < 8; ++it) {
        int l = it * 4 + li;
        tl[l][ho] = u[(size_t)(b * L_SEQ + lt * 32 + l) * H_DIM + ht * 64 + ho];
    }
    __syncthreads();
    int hh = t >> 2, lrun = (t & 3) * 8;
    bf16x8 v;
    #pragma unroll
    for (int i = 0; i < 8; ++i) v[i] = (__bf16)tl[lrun + i][hh];
    *(bf16x8*)(ut + (size_t)(ht * 64 + hh) * 32768 + b * 4096 + lt * 32 + lrun) = v;
}

// ---------------- K1: per-chunk end states from ut (bf16 streaming) ----------------
template<int DIR>
__device__ __forceinline__ void state_body(
    int tid, const __bf16* __restrict__ ut, const float* __restrict__ pA,
    __bf16* __restrict__ S)
{
    int q = tid & 3, h = (tid >> 2) & 511, c = (tid >> 11) & 15, b = (tid >> 15) & 7;
    const f32x4* Ap = (const f32x4*)(pA + (size_t)(DIR * 512 + h) * 64 + q * 16);
    float A[16], x[16];
    #pragma unroll
    for (int i = 0; i < 4; ++i) {
        f32x4 a = Ap[i];
        A[4*i+0]=a[0]; A[4*i+1]=a[1]; A[4*i+2]=a[2]; A[4*i+3]=a[3];
        x[4*i+0]=0.f;  x[4*i+1]=0.f;  x[4*i+2]=0.f;  x[4*i+3]=0.f;
    }
    int off = h * 32768 + b * 4096 + (DIR ? (c * 256 + 248) : c * 256);
    const int vstep = DIR ? -8 : 8;
    bf16x8 v = *(const bf16x8*)(ut + off);
    for (int blk = 0; blk < 31; ++blk) {
        off += vstep;
        bf16x8 nv = *(const bf16x8*)(ut + off);
        #pragma unroll
        for (int jj = 0; jj < 8; ++jj) {
            float cur = (float)v[DIR ? 7 - jj : jj];
            #pragma unroll
            for (int i = 0; i < 16; ++i) x[i] = fmaf(A[i], x[i], cur);
        }
        v = nv;
    }
    #pragma unroll
    for (int jj = 0; jj < 8; ++jj) {
        float cur = (float)v[DIR ? 7 - jj : jj];
        #pragma unroll
        for (int i = 0; i < 16; ++i) x[i] = fmaf(A[i], x[i], cur);
    }
    size_t soff = ((((size_t)DIR * N_CH + c) * N_B + b) * H_DIM + h) * N_ST + q * 16;
    bf16x8 o0, o1;
    #pragma unroll
    for (int i = 0; i < 8; ++i) { o0[i] = (__bf16)x[i]; o1[i] = (__bf16)x[8 + i]; }
    *(bf16x8*)(S + soff) = o0;
    *(bf16x8*)(S + soff + 8) = o1;
}

__global__ __launch_bounds__(256) void k_state(
    const __bf16* __restrict__ ut, const float* __restrict__ pA,
    __bf16* __restrict__ S)
{
    int tid = blockIdx.x * 256 + threadIdx.x;      // 524288
    if (tid >> 18) state_body<1>(tid, ut, pA, S);
    else           state_body<0>(tid, ut, pA, S);
}

// ---------------- K2: inter-chunk scan (bf16 S, in place) ----------------
__global__ __launch_bounds__(256) void k_chunkscan(
    const float* __restrict__ pPW, __bf16* __restrict__ S)
{
    int tid = blockIdx.x * 256 + threadIdx.x;      // 524288
    int n   = tid & 63;
    int h   = (tid >> 6) & 511;
    int b   = (tid >> 15) & 7;
    int dir = tid >> 18;
    float pw = pPW[((size_t)(dir * H_DIM + h)) * N_ST + n];
    float X = 0.f;
    for (int i = 0; i < N_CH; ++i) {
        int c = dir ? (N_CH - 1 - i) : i;
        size_t a = ((((size_t)dir * N_CH + c) * N_B + b) * H_DIM + h) * N_ST + n;
        float tmp = (float)S[a];
        S[a] = (__bf16)X;                 // incoming state for chunk c
        X = fmaf(pw, X, tmp);
    }
}

// ---------------- k_conv v4: LDS-staged MFMA chunk conv ----------------
// Same as v3 except the epilogue writes yc2 in the PRE-SWIZZLED k_gemm A-tile
// image: yc2[mt][ktile][8KB] with byte = kgrp*2048 + (mi*16 ^ ((mi>>3&7)<<4))
// + ke*2  (mt=m>>7, mi=m&127, ktile=k>>5, kgrp=(k>>3)&3, ke=k&7).
template<int DIR>
__device__ __forceinline__ void conv_body(
    int h, int t,
    const float* __restrict__ kk, const float* __restrict__ pLG,
    const float* __restrict__ pCB, const float* __restrict__ Dv,
    const __bf16* __restrict__ ut, const __bf16* __restrict__ S,
    char* __restrict__ yc2,
    __bf16* uts, ull* kkq8, float* slg, float* scb)
{
    int dirh = DIR * 512 + h;
    int lane = t & 63, w = t >> 6;
    int lr = lane & 15, lg = lane >> 4;

    unsigned short* asc = (unsigned short*)uts;
    for (int i = t; i < 548; i += 512) {
        int d = DIR ? (i - 272) : (271 - i);
        float kv = (d >= 0 && d < 256) ? kk[dirh * 256 + d] : 0.f;
        asc[i] = __builtin_bit_cast(unsigned short, (__bf16)kv);
    }
    if (t < 64)       slg[t]      = pLG[dirh * 64 + t];
    else if (t < 128) scb[t - 64] = pCB[dirh * 64 + (t - 64)];
    __syncthreads();
    for (int i = t; i < 544; i += 512)
        kkq8[i] = (ull)asc[i] | ((ull)asc[i+1] << 16) | ((ull)asc[i+2] << 32)
                | ((ull)asc[i+3] << 48);
    __syncthreads();

    float Dh = Dv[h];
    const ull* kq = kkq8;
    // invariant part of the yc2 address for this (dir,h) = k index
    char* ybase = yc2 + (size_t)(dirh >> 5) * 8192
                + (((dirh >> 3) & 3) * 2048) + ((dirh & 7) * 2);

    for (int hf = 0; hf < 2; ++hf) {
        #pragma unroll
        for (int i = 0; i < 4; ++i) {
            int chunk = i * 512 + t;          // 0..2047
            int col   = chunk >> 5;
            int l8    = (chunk & 31) << 3;
            int l8s   = l8 ^ ((col & 7) << 3);
            GLOAD16(ut + (size_t)h * 32768 + (hf * 64 + col) * 256 + l8s,
                    (char*)uts + chunk * 16);
        }
        __syncthreads();

        f32x4 acc[2][4] = {};

        #pragma unroll
        for (int mf = 0; mf < 2; ++mf) {
            int rt  = mf ? (15 - w) : w;
            int jlo = DIR ? (rt >> 1) : 0;
            int jhi = DIR ? 8 : ((rt >> 1) + 1);
            int sb  = (DIR ? 272 : 271) + lg * 8 - rt * 16 - lr;
            for (int jt = jlo; jt < jhi; ++jt) {
                bf16x8 bv[4];
                #pragma unroll
                for (int n = 0; n < 4; ++n) {
                    int col = n * 16 + lr;
                    bv[n] = *(const bf16x8*)((char*)uts + col * 512
                              + (((jt * 4 + lg) ^ (col & 7)) << 4));
                }
                int si = sb + jt * 32;
                ull lo = kq[si], hi = kq[si + 4];
                bf16x8 av;
                ((ull*)&av)[0] = lo; ((ull*)&av)[1] = hi;
                #pragma unroll
                for (int n = 0; n < 4; ++n)
                    acc[mf][n] = __builtin_amdgcn_mfma_f32_16x16x32_bf16(av, bv[n], acc[mf][n], 0, 0, 0);
            }
        }

        #pragma unroll
        for (int nt = 0; nt < 2; ++nt) {
            bf16x8 bs[4];
            #pragma unroll
            for (int n = 0; n < 4; ++n) {
                size_t soff = ((((size_t)DIR * N_CH + lr) * N_B + (hf * 4 + n)) * H_DIM + h)
                              * N_ST + nt * 32 + lg * 8;
                bs[n] = *(const bf16x8*)(S + soff);
            }
            #pragma unroll
            for (int mf = 0; mf < 2; ++mf) {
                int rt = mf ? (15 - w) : w;
                int l  = rt * 16 + lr;
                float e = DIR ? (float)(256 - l) : (float)(l + 1);
                bf16x8 gv;
                #pragma unroll
                for (int j = 0; j < 8; ++j) {
                    int n = nt * 32 + lg * 8 + j;
                    gv[j] = (__bf16)(scb[n] * exp2f(e * slg[n]));
                }
                #pragma unroll
                for (int n = 0; n < 4; ++n)
                    acc[mf][n] = __builtin_amdgcn_mfma_f32_16x16x32_bf16(gv, bs[n], acc[mf][n], 0, 0, 0);
            }
        }

        // ---- epilogue: + D*u, write yc2 (pre-swizzled A-tile image) ----
        #pragma unroll
        for (int mf = 0; mf < 2; ++mf) {
            int rt = mf ? (15 - w) : w;
            int l0 = rt * 16 + lg * 4;
            #pragma unroll
            for (int n = 0; n < 4; ++n) {
                int col = n * 16 + lr;
                bf16x4 uv = *(const bf16x4*)((char*)uts + col * 512
                             + ((((l0 >> 3) ^ (col & 7)) << 4) | ((l0 & 7) * 2)));
                int m0  = ((hf * 64 + col) << 8) + l0;   // global m, mult of 4
                int mt  = m0 >> 7;
                int mi0 = m0 & 127;
                int swz = ((mi0 >> 3) & 7) << 4;
                char* bp = ybase + (size_t)mt * 262144;
                #pragma unroll
                for (int r = 0; r < 4; ++r) {
                    __bf16 ov = (__bf16)(acc[mf][n][r] + Dh * (float)uv[r]);
                    *(unsigned short*)(bp + (((mi0 + r) * 16) ^ swz)) =
                        __builtin_bit_cast(unsigned short, ov);
                }
            }
        }
        __syncthreads();
    }
}

__global__ __launch_bounds__(512, 4) void k_conv(
    const float* __restrict__ kk, const float* __restrict__ pLG,
    const float* __restrict__ pCB, const float* __restrict__ Dv,
    const __bf16* __restrict__ ut, const __bf16* __restrict__ S,
    char* __restrict__ yc2)
{
    __shared__ __bf16 uts[16384];
    __shared__ ull kkq8[544];
    __shared__ float slg[64], scb[64];
    int h = blockIdx.x & 511;
    int t = threadIdx.x;
    if (blockIdx.x >> 9)
        conv_body<1>(h, t, kk, pLG, pCB, Dv, ut, S, yc2, uts, kkq8, slg, scb);
    else
        conv_body<0>(h, t, kk, pLG, pCB, Dv, ut, S, yc2, uts, kkq8, slg, scb);
}

// ---------------- K4 v5: out = ycat @ W^T + bias ----------------
// A-tile: verbatim 8KB global_load_lds copy of yc2's pre-swizzled image;
// reads identical to the R9-verified path. B: swizzled GLOAD16. N-tile 256.
__global__ __launch_bounds__(256, 2) void k_gemm(
    const char* __restrict__ yc2, const __bf16* __restrict__ B,
    const float* __restrict__ bias, float* __restrict__ out)
{
    __shared__ __bf16 As[4][128][8];    // 8 KB, [k>>3][m][k&7], XOR-swizzled
    __shared__ __bf16 Bs[256][32];      // 16 KB, unit-XOR swizzled
    int t  = threadIdx.x;
    int l  = t & 63, w = t >> 6;
    int lr = l & 15, lg = l >> 4;
    int mBase = blockIdx.y * 128;
    int nBase = blockIdx.x * 256;
    int wr = (w >> 1) * 64, wc = (w & 1) * 128;

    char* AsB = (char*)&As[0][0][0];
    char* BsB = (char*)&Bs[0][0];
    f32x4 acc[4][8] = {};

    const char* abase = yc2 + (size_t)(mBase >> 7) * 262144;

    for (int kt = 0; kt < K_GEMM; kt += 32) {
        __syncthreads();
        // A tile: verbatim 8KB copy of the pre-swizzled image
        #pragma unroll
        for (int i = 0; i < 2; ++i) {
            int c = i * 256 + t;              // 0..511
            GLOAD16(abase + (size_t)(kt >> 5) * 8192 + c * 16, AsB + c * 16);
        }
        // B tile via global_load_lds, source pre-swizzled: kq ^= (row>>1)&3
        #pragma unroll
        for (int i = 0; i < 4; ++i) {
            int chunk = i * 256 + t;          // 0..1023
            int row = chunk >> 2, kq = chunk & 3;
            int kqs = kq ^ ((row >> 1) & 3);
            GLOAD16(B + (size_t)(nBase + row) * K_GEMM + kt + kqs * 8,
                    BsB + chunk * 16);
        }
        __syncthreads();
        bf16x8 af[4], bfv[8];
        #pragma unroll
        for (int m = 0; m < 4; ++m) {
            int row = wr + m * 16 + lr;
            int off = ((lg * 128 + row) * 16) ^ (((row >> 3) & 7) << 4);
            af[m] = *(const bf16x8*)(AsB + off);
        }
        #pragma unroll
        for (int n = 0; n < 8; ++n) {
            int row = wc + n * 16 + lr;
            bfv[n] = *(const bf16x8*)(BsB + row * 64
                       + ((lg * 16) ^ (((row >> 1) & 3) << 4)));
        }
        #pragma unroll
        for (int m = 0; m < 4; ++m)
            #pragma unroll
            for (int n = 0; n < 8; ++n)
                acc[m][n] = __builtin_amdgcn_mfma_f32_16x16x32_bf16(af[m], bfv[n], acc[m][n], 0, 0, 0);
    }

    #pragma unroll
    for (int n = 0; n < 8; ++n) {
        int colg = nBase + wc + n * 16 + lr;
        float bv = bias[colg];
        #pragma unroll
        for (int m = 0; m < 4; ++m) {
            int rowg = mBase + wr + m * 16 + lg * 4;
            #pragma unroll
            for (int r = 0; r < 4; ++r)
                out[(size_t)(rowg + r) * H_DIM + colg] = acc[m][n][r] + bv;
        }
    }
}

extern "C" void kernel_launch(void* const* d_in, const int* in_sizes, int n_in,
                              void* d_out, int out_size, void* d_ws, size_t ws_size,
                              hipStream_t stream)
{
    const float* u       = (const float*)d_in[0];
    const float* A_log   = (const float*)d_in[1];
    const float* Bv      = (const float*)d_in[2];
    const float* C       = (const float*)d_in[3];
    const float* D       = (const float*)d_in[4];
    const float* log_dt  = (const float*)d_in[5];
    const float* A_log_r = (const float*)d_in[6];
    const float* B_r     = (const float*)d_in[7];
    const float* C_r     = (const float*)d_in[8];
    const float* W_bi    = (const float*)d_in[9];
    const float* b_bi    = (const float*)d_in[10];
    float* out = (float*)d_out;

    char* ws = (char*)d_ws;
    float* pA   = (float*)(ws + 0x000000);   // 256 KiB
    float* pCB  = (float*)(ws + 0x040000);
    float* pPW  = (float*)(ws + 0x080000);
    float* pLG  = (float*)(ws + 0x0C0000);
    float* kk   = (float*)(ws + 0x100000);   // 1 MiB
    __bf16* Wbf = (__bf16*)(ws + 0x200000);  // 1 MiB
    __bf16* S   = (__bf16*)(ws + 0x300000);  // 16 MiB
    __bf16* ut  = (__bf16*)(ws + 0x1300000); // 32 MiB
    char*   yc2 = (char*)  (ws + 0x3300000); // 64 MiB  (end 115 MiB)

    k_precompute<<<256,  256, 0, stream>>>(A_log, Bv, C, log_dt, A_log_r, B_r, C_r,
                                           pA, pCB, pPW, pLG);
    k_convw     <<<2048, 256, 0, stream>>>(W_bi, Wbf);
    k_kk        <<<1024, 256, 0, stream>>>(pCB, pLG, kk);
    k_ut        <<<8192, 256, 0, stream>>>(u, ut);
    k_state     <<<2048, 256, 0, stream>>>(ut, pA, S);
    k_chunkscan <<<2048, 256, 0, stream>>>(pPW, S);
    k_conv      <<<1024, 512, 0, stream>>>(kk, pLG, pCB, D, ut, S, yc2);
    dim3 g(2, 256);
    k_gemm      <<<g,    256, 0, stream>>>(yc2, Wbf, b_bi, out);
}

// Round 11
// 187.231 us; speedup vs baseline: 1.7319x; 1.7319x over previous
//
#include <hip/hip_runtime.h>
#include <hip/hip_bf16.h>
#include <stdint.h>

#define L_SEQ  4096
#define H_DIM  512
#define N_ST   64
#define N_B    8
#define N_CH   16
#define T_CH   256
#define K_GEMM 1024

typedef float  f32x4  __attribute__((ext_vector_type(4)));
typedef __bf16 bf16x8 __attribute__((ext_vector_type(8)));
typedef __bf16 bf16x4 __attribute__((ext_vector_type(4)));
typedef unsigned short u16x8 __attribute__((ext_vector_type(8)));
typedef unsigned long long ull;

#define GLOAD16(g, l) __builtin_amdgcn_global_load_lds( \
    (const __attribute__((address_space(1))) void*)(g), \
    (__attribute__((address_space(3))) void*)(l), 16, 0, 0)

// ---------------- K0: precompute A_bar, C*B_bar, A_bar^T, log2(A_bar) ----------------
__global__ __launch_bounds__(256) void k_precompute(
    const float* __restrict__ A_log, const float* __restrict__ Bv,
    const float* __restrict__ C, const float* __restrict__ log_dt,
    const float* __restrict__ A_log_r, const float* __restrict__ B_r,
    const float* __restrict__ C_r,
    float* __restrict__ pA, float* __restrict__ pCB, float* __restrict__ pPW,
    float* __restrict__ pLG)
{
    int tid = blockIdx.x * 256 + threadIdx.x;      // 2*512*64
    int n   = tid & 63;
    int h   = (tid >> 6) & 511;
    int dir = tid >> 15;
    float dt = expf(log_dt[h]);
    const float* Al = dir ? A_log_r : A_log;
    const float* Bp = dir ? B_r    : Bv;
    const float* Cp = dir ? C_r    : C;
    float eA = expf(Al[h * N_ST + n]);
    float Ab = expf(-dt * eA);
    float Bb = (1.0f - Ab) / eA * Bp[h * N_ST + n];
    pA[tid]  = Ab;
    pCB[tid] = Cp[h * N_ST + n] * Bb;
    pPW[tid] = expf(-dt * eA * (float)T_CH);
    pLG[tid] = -dt * eA * 1.44269504088896f;       // log2(A_bar)
}

// ---------------- Kw: W_bi f32 -> bf16 ----------------
__global__ __launch_bounds__(256) void k_convw(
    const float* __restrict__ W, __bf16* __restrict__ Wbf)
{
    int tid = blockIdx.x * 256 + threadIdx.x;
    Wbf[tid] = (__bf16)W[tid];
}

// ---------------- k_kk: conv kernel taps kk[dirh][d] = sum_n CB_n A_n^d ----------------
__global__ __launch_bounds__(256) void k_kk(
    const float* __restrict__ pCB, const float* __restrict__ pLG,
    float* __restrict__ kk)
{
    __shared__ float scb[64], slg[64];
    int dirh = blockIdx.x;           // 0..1023
    int d = threadIdx.x;             // 0..255
    if (d < 64) { scb[d] = pCB[dirh * 64 + d]; slg[d] = pLG[dirh * 64 + d]; }
    __syncthreads();
    float s = 0.f;
    #pragma unroll
    for (int n = 0; n < 64; ++n) s += scb[n] * exp2f((float)d * slg[n]);
    kk[dirh * 256 + d] = s;
}

// ---------------- k_ut: u [b,l,h] f32 -> ut [h][b][l] bf16 ----------------
__global__ __launch_bounds__(256) void k_ut(
    const float* __restrict__ u, __bf16* __restrict__ ut)
{
    __shared__ float tl[32][65];
    int blk = blockIdx.x;            // 128 l-tiles * 8 h-tiles * 8 b
    int lt = blk & 127, ht = (blk >> 7) & 7, b = blk >> 10;
    int t = threadIdx.x;
    int ho = t & 63, li = t >> 6;
    #pragma unroll
    for (int it = 0; it < 8; ++it) {
        int l = it * 4 + li;
        tl[l][ho] = u[(size_t)(b * L_SEQ + lt * 32 + l) * H_DIM + ht * 64 + ho];
    }
    __syncthreads();
    int hh = t >> 2, lrun = (t & 3) * 8;
    bf16x8 v;
    #pragma unroll
    for (int i = 0; i < 8; ++i) v[i] = (__bf16)tl[lrun + i][hh];
    *(bf16x8*)(ut + (size_t)(ht * 64 + hh) * 32768 + b * 4096 + lt * 32 + lrun) = v;
}

// ---------------- K1: per-chunk end states from ut (bf16 streaming) ----------------
template<int DIR>
__device__ __forceinline__ void state_body(
    int tid, const __bf16* __restrict__ ut, const float* __restrict__ pA,
    __bf16* __restrict__ S)
{
    int q = tid & 3, h = (tid >> 2) & 511, c = (tid >> 11) & 15, b = (tid >> 15) & 7;
    const f32x4* Ap = (const f32x4*)(pA + (size_t)(DIR * 512 + h) * 64 + q * 16);
    float A[16], x[16];
    #pragma unroll
    for (int i = 0; i < 4; ++i) {
        f32x4 a = Ap[i];
        A[4*i+0]=a[0]; A[4*i+1]=a[1]; A[4*i+2]=a[2]; A[4*i+3]=a[3];
        x[4*i+0]=0.f;  x[4*i+1]=0.f;  x[4*i+2]=0.f;  x[4*i+3]=0.f;
    }
    int off = h * 32768 + b * 4096 + (DIR ? (c * 256 + 248) : c * 256);
    const int vstep = DIR ? -8 : 8;
    bf16x8 v = *(const bf16x8*)(ut + off);
    for (int blk = 0; blk < 31; ++blk) {
        off += vstep;
        bf16x8 nv = *(const bf16x8*)(ut + off);
        #pragma unroll
        for (int jj = 0; jj < 8; ++jj) {
            float cur = (float)v[DIR ? 7 - jj : jj];
            #pragma unroll
            for (int i = 0; i < 16; ++i) x[i] = fmaf(A[i], x[i], cur);
        }
        v = nv;
    }
    #pragma unroll
    for (int jj = 0; jj < 8; ++jj) {
        float cur = (float)v[DIR ? 7 - jj : jj];
        #pragma unroll
        for (int i = 0; i < 16; ++i) x[i] = fmaf(A[i], x[i], cur);
    }
    size_t soff = ((((size_t)DIR * N_CH + c) * N_B + b) * H_DIM + h) * N_ST + q * 16;
    bf16x8 o0, o1;
    #pragma unroll
    for (int i = 0; i < 8; ++i) { o0[i] = (__bf16)x[i]; o1[i] = (__bf16)x[8 + i]; }
    *(bf16x8*)(S + soff) = o0;
    *(bf16x8*)(S + soff + 8) = o1;
}

__global__ __launch_bounds__(256) void k_state(
    const __bf16* __restrict__ ut, const float* __restrict__ pA,
    __bf16* __restrict__ S)
{
    int tid = blockIdx.x * 256 + threadIdx.x;      // 524288
    if (tid >> 18) state_body<1>(tid, ut, pA, S);
    else           state_body<0>(tid, ut, pA, S);
}

// ---------------- K2: inter-chunk scan (bf16 S, in place) ----------------
__global__ __launch_bounds__(256) void k_chunkscan(
    const float* __restrict__ pPW, __bf16* __restrict__ S)
{
    int tid = blockIdx.x * 256 + threadIdx.x;      // 524288
    int n   = tid & 63;
    int h   = (tid >> 6) & 511;
    int b   = (tid >> 15) & 7;
    int dir = tid >> 18;
    float pw = pPW[((size_t)(dir * H_DIM + h)) * N_ST + n];
    float X = 0.f;
    for (int i = 0; i < N_CH; ++i) {
        int c = dir ? (N_CH - 1 - i) : i;
        size_t a = ((((size_t)dir * N_CH + c) * N_B + b) * H_DIM + h) * N_ST + n;
        float tmp = (float)S[a];
        S[a] = (__bf16)X;                 // incoming state for chunk c
        X = fmaf(pw, X, tmp);
    }
}

// ---------------- k_conv v3 (R9-verified): LDS-staged MFMA chunk conv ----------------
template<int DIR>
__device__ __forceinline__ void conv_body(
    int h, int t,
    const float* __restrict__ kk, const float* __restrict__ pLG,
    const float* __restrict__ pCB, const float* __restrict__ Dv,
    const __bf16* __restrict__ ut, const __bf16* __restrict__ S,
    __bf16* __restrict__ ycT,
    __bf16* uts, ull* kkq8, float* slg, float* scb)
{
    int dirh = DIR * 512 + h;
    int lane = t & 63, w = t >> 6;
    int lr = lane & 15, lg = lane >> 4;

    unsigned short* asc = (unsigned short*)uts;
    for (int i = t; i < 548; i += 512) {
        int d = DIR ? (i - 272) : (271 - i);
        float kv = (d >= 0 && d < 256) ? kk[dirh * 256 + d] : 0.f;
        asc[i] = __builtin_bit_cast(unsigned short, (__bf16)kv);
    }
    if (t < 64)       slg[t]      = pLG[dirh * 64 + t];
    else if (t < 128) scb[t - 64] = pCB[dirh * 64 + (t - 64)];
    __syncthreads();
    for (int i = t; i < 544; i += 512)
        kkq8[i] = (ull)asc[i] | ((ull)asc[i+1] << 16) | ((ull)asc[i+2] << 32)
                | ((ull)asc[i+3] << 48);
    __syncthreads();

    float Dh = Dv[h];
    const ull* kq = kkq8;

    for (int hf = 0; hf < 2; ++hf) {
        #pragma unroll
        for (int i = 0; i < 4; ++i) {
            int chunk = i * 512 + t;          // 0..2047
            int col   = chunk >> 5;
            int l8    = (chunk & 31) << 3;
            int l8s   = l8 ^ ((col & 7) << 3);
            GLOAD16(ut + (size_t)h * 32768 + (hf * 64 + col) * 256 + l8s,
                    (char*)uts + chunk * 16);
        }
        __syncthreads();

        f32x4 acc[2][4] = {};

        #pragma unroll
        for (int mf = 0; mf < 2; ++mf) {
            int rt  = mf ? (15 - w) : w;
            int jlo = DIR ? (rt >> 1) : 0;
            int jhi = DIR ? 8 : ((rt >> 1) + 1);
            int sb  = (DIR ? 272 : 271) + lg * 8 - rt * 16 - lr;
            for (int jt = jlo; jt < jhi; ++jt) {
                bf16x8 bv[4];
                #pragma unroll
                for (int n = 0; n < 4; ++n) {
                    int col = n * 16 + lr;
                    bv[n] = *(const bf16x8*)((char*)uts + col * 512
                              + (((jt * 4 + lg) ^ (col & 7)) << 4));
                }
                int si = sb + jt * 32;
                ull lo = kq[si], hi = kq[si + 4];
                bf16x8 av;
                ((ull*)&av)[0] = lo; ((ull*)&av)[1] = hi;
                #pragma unroll
                for (int n = 0; n < 4; ++n)
                    acc[mf][n] = __builtin_amdgcn_mfma_f32_16x16x32_bf16(av, bv[n], acc[mf][n], 0, 0, 0);
            }
        }

        #pragma unroll
        for (int nt = 0; nt < 2; ++nt) {
            bf16x8 bs[4];
            #pragma unroll
            for (int n = 0; n < 4; ++n) {
                size_t soff = ((((size_t)DIR * N_CH + lr) * N_B + (hf * 4 + n)) * H_DIM + h)
                              * N_ST + nt * 32 + lg * 8;
                bs[n] = *(const bf16x8*)(S + soff);
            }
            #pragma unroll
            for (int mf = 0; mf < 2; ++mf) {
                int rt = mf ? (15 - w) : w;
                int l  = rt * 16 + lr;
                float e = DIR ? (float)(256 - l) : (float)(l + 1);
                bf16x8 gv;
                #pragma unroll
                for (int j = 0; j < 8; ++j) {
                    int n = nt * 32 + lg * 8 + j;
                    gv[j] = (__bf16)(scb[n] * exp2f(e * slg[n]));
                }
                #pragma unroll
                for (int n = 0; n < 4; ++n)
                    acc[mf][n] = __builtin_amdgcn_mfma_f32_16x16x32_bf16(gv, bs[n], acc[mf][n], 0, 0, 0);
            }
        }

        #pragma unroll
        for (int mf = 0; mf < 2; ++mf) {
            int rt = mf ? (15 - w) : w;
            int l0 = rt * 16 + lg * 4;
            #pragma unroll
            for (int n = 0; n < 4; ++n) {
                int col = n * 16 + lr;
                bf16x4 uv = *(const bf16x4*)((char*)uts + col * 512
                             + ((((l0 >> 3) ^ (col & 7)) << 4) | ((l0 & 7) * 2)));
                bf16x4 o;
                #pragma unroll
                for (int r = 0; r < 4; ++r)
                    o[r] = (__bf16)(acc[mf][n][r] + Dh * (float)uv[r]);
                *(bf16x4*)(ycT + (size_t)dirh * 32768 + (hf * 64 + col) * 256 + l0) = o;
            }
        }
        __syncthreads();
    }
}

__global__ __launch_bounds__(512, 4) void k_conv(
    const float* __restrict__ kk, const float* __restrict__ pLG,
    const float* __restrict__ pCB, const float* __restrict__ Dv,
    const __bf16* __restrict__ ut, const __bf16* __restrict__ S,
    __bf16* __restrict__ ycT)
{
    __shared__ __bf16 uts[16384];
    __shared__ ull kkq8[544];
    __shared__ float slg[64], scb[64];
    int h = blockIdx.x & 511;
    int t = threadIdx.x;
    if (blockIdx.x >> 9)
        conv_body<1>(h, t, kk, pLG, pCB, Dv, ut, S, ycT, uts, kkq8, slg, scb);
    else
        conv_body<0>(h, t, kk, pLG, pCB, Dv, ut, S, ycT, uts, kkq8, slg, scb);
}

// ---------------- K4 v6: 2-phase double-buffered GEMM ----------------
// A: reg-staged scalar transpose into swizzled As (R9-verified layout);
// B: swizzled GLOAD16. One raw barrier per K-step; loads in flight under MFMA.
__global__ __launch_bounds__(256, 2) void k_gemm(
    const __bf16* __restrict__ ycT, const __bf16* __restrict__ B,
    const float* __restrict__ bias, float* __restrict__ out)
{
    __shared__ __bf16 As[2][4][128][8];    // 16 KB
    __shared__ __bf16 Bs[2][256][32];      // 32 KB
    int t  = threadIdx.x;
    int l  = t & 63, w = t >> 6;
    int lr = l & 15, lg = l >> 4;
    int mBase = blockIdx.y * 128;
    int nBase = blockIdx.x * 256;
    int wr = (w >> 1) * 64, wc = (w & 1) * 128;

    int sT  = t & 15;           // m-octet
    int skk = t >> 4;           // k 0..15
    int swz = (sT & 7) << 4;

    f32x4 acc[4][8] = {};
    const __bf16* aptr = ycT + mBase + sT * 8;

#define STAGE_A(buf, va0, va1) do { \
    char* AsB_ = (char*)&As[buf][0][0][0]; \
    _Pragma("unroll") \
    for (int p = 0; p < 2; ++p) { \
        int kk_ = skk + p * 16; \
        u16x8 av_ = p ? (va1) : (va0); \
        int kgrp_ = kk_ >> 3, ke_ = kk_ & 7; \
        _Pragma("unroll") \
        for (int i = 0; i < 8; ++i) { \
            int off_ = ((kgrp_ * 128 + sT * 8 + i) * 16 + ke_ * 2) ^ swz; \
            *(unsigned short*)(AsB_ + off_) = av_[i]; \
        } \
    } } while (0)

#define STAGE_B(buf, kt_) do { \
    char* BsB_ = (char*)&Bs[buf][0][0]; \
    _Pragma("unroll") \
    for (int i = 0; i < 4; ++i) { \
        int chunk_ = i * 256 + t; \
        int row_ = chunk_ >> 2, kq_ = chunk_ & 3; \
        int kqs_ = kq_ ^ ((row_ >> 1) & 3); \
        GLOAD16(B + (size_t)(nBase + row_) * K_GEMM + (kt_) + kqs_ * 8, \
                BsB_ + chunk_ * 16); \
    } } while (0)

#define COMPUTE(buf) do { \
    char* AsB_ = (char*)&As[buf][0][0][0]; \
    char* BsB_ = (char*)&Bs[buf][0][0]; \
    bf16x8 af_[4], bfv_[8]; \
    _Pragma("unroll") \
    for (int m = 0; m < 4; ++m) { \
        int row_ = wr + m * 16 + lr; \
        int off_ = ((lg * 128 + row_) * 16) ^ (((row_ >> 3) & 7) << 4); \
        af_[m] = *(const bf16x8*)(AsB_ + off_); \
    } \
    _Pragma("unroll") \
    for (int n = 0; n < 8; ++n) { \
        int row_ = wc + n * 16 + lr; \
        bfv_[n] = *(const bf16x8*)(BsB_ + row_ * 64 \
                    + ((lg * 16) ^ (((row_ >> 1) & 3) << 4))); \
    } \
    _Pragma("unroll") \
    for (int m = 0; m < 4; ++m) \
        _Pragma("unroll") \
        for (int n = 0; n < 8; ++n) \
            acc[m][n] = __builtin_amdgcn_mfma_f32_16x16x32_bf16(af_[m], bfv_[n], acc[m][n], 0, 0, 0); \
    } while (0)

    // ---- prologue: stage tile 0, preload tile-1 regs ----
    u16x8 a0 = *(const u16x8*)(aptr + (size_t)skk * 32768);
    u16x8 a1 = *(const u16x8*)(aptr + (size_t)(skk + 16) * 32768);
    STAGE_A(0, a0, a1);
    STAGE_B(0, 0);
    asm volatile("s_waitcnt vmcnt(0)" ::: "memory");
    __builtin_amdgcn_sched_barrier(0);
    a0 = *(const u16x8*)(aptr + (size_t)(32 + skk) * 32768);
    a1 = *(const u16x8*)(aptr + (size_t)(48 + skk) * 32768);
    __builtin_amdgcn_sched_barrier(0);
    asm volatile("s_waitcnt lgkmcnt(0)" ::: "memory");
    __builtin_amdgcn_s_barrier();

    int cur = 0;
    for (int kt = 0; kt < K_GEMM - 32; kt += 32) {
        int nxt = cur ^ 1;
        STAGE_A(nxt, a0, a1);          // compiler waits the year-old a-loads
        STAGE_B(nxt, kt + 32);         // 4 GLOAD16 in flight under compute
        COMPUTE(cur);
        asm volatile("s_waitcnt vmcnt(0)" ::: "memory");
        __builtin_amdgcn_sched_barrier(0);
        if (kt + 64 < K_GEMM) {
            a0 = *(const u16x8*)(aptr + (size_t)(kt + 64 + skk) * 32768);
            a1 = *(const u16x8*)(aptr + (size_t)(kt + 80 + skk) * 32768);
        }
        __builtin_amdgcn_sched_barrier(0);
        asm volatile("s_waitcnt lgkmcnt(0)" ::: "memory");
        __builtin_amdgcn_s_barrier();
        cur = nxt;
    }
    COMPUTE(cur);                      // epilogue tile (no prefetch)

#undef STAGE_A
#undef STAGE_B
#undef COMPUTE

    #pragma unroll
    for (int n = 0; n < 8; ++n) {
        int colg = nBase + wc + n * 16 + lr;
        float bv = bias[colg];
        #pragma unroll
        for (int m = 0; m < 4; ++m) {
            int rowg = mBase + wr + m * 16 + lg * 4;
            #pragma unroll
            for (int r = 0; r < 4; ++r)
                out[(size_t)(rowg + r) * H_DIM + colg] = acc[m][n][r] + bv;
        }
    }
}

extern "C" void kernel_launch(void* const* d_in, const int* in_sizes, int n_in,
                              void* d_out, int out_size, void* d_ws, size_t ws_size,
                              hipStream_t stream)
{
    const float* u       = (const float*)d_in[0];
    const float* A_log   = (const float*)d_in[1];
    const float* Bv      = (const float*)d_in[2];
    const float* C       = (const float*)d_in[3];
    const float* D       = (const float*)d_in[4];
    const float* log_dt  = (const float*)d_in[5];
    const float* A_log_r = (const float*)d_in[6];
    const float* B_r     = (const float*)d_in[7];
    const float* C_r     = (const float*)d_in[8];
    const float* W_bi    = (const float*)d_in[9];
    const float* b_bi    = (const float*)d_in[10];
    float* out = (float*)d_out;

    char* ws = (char*)d_ws;
    float* pA   = (float*)(ws + 0x000000);   // 256 KiB
    float* pCB  = (float*)(ws + 0x040000);
    float* pPW  = (float*)(ws + 0x080000);
    float* pLG  = (float*)(ws + 0x0C0000);
    float* kk   = (float*)(ws + 0x100000);   // 1 MiB
    __bf16* Wbf = (__bf16*)(ws + 0x200000);  // 1 MiB
    __bf16* S   = (__bf16*)(ws + 0x300000);  // 16 MiB
    __bf16* ut  = (__bf16*)(ws + 0x1300000); // 32 MiB
    __bf16* ycT = (__bf16*)(ws + 0x3300000); // 64 MiB  (end 115 MiB)

    k_precompute<<<256,  256, 0, stream>>>(A_log, Bv, C, log_dt, A_log_r, B_r, C_r,
                                           pA, pCB, pPW, pLG);
    k_convw     <<<2048, 256, 0, stream>>>(W_bi, Wbf);
    k_kk        <<<1024, 256, 0, stream>>>(pCB, pLG, kk);
    k_ut        <<<8192, 256, 0, stream>>>(u, ut);
    k_state     <<<2048, 256, 0, stream>>>(ut, pA, S);
    k_chunkscan <<<2048, 256, 0, stream>>>(pPW, S);
    k_conv      <<<1024, 512, 0, stream>>>(kk, pLG, pCB, D, ut, S, ycT);
    dim3 g(2, 256);
    k_gemm      <<<g,    256, 0, stream>>>(ycT, Wbf, b_bi, out);
}

// Round 12
// 147.034 us; speedup vs baseline: 2.2054x; 1.2734x over previous
//
#include <hip/hip_runtime.h>
#include <hip/hip_bf16.h>
#include <stdint.h>

#define L_SEQ  4096
#define H_DIM  512
#define N_ST   64
#define N_B    8
#define N_CH   16
#define T_CH   256
#define K_GEMM 1024

typedef float  f32x4  __attribute__((ext_vector_type(4)));
typedef __bf16 bf16x8 __attribute__((ext_vector_type(8)));
typedef __bf16 bf16x4 __attribute__((ext_vector_type(4)));
typedef unsigned short u16x8 __attribute__((ext_vector_type(8)));
typedef unsigned long long ull;

#define GLOAD16(g, l) __builtin_amdgcn_global_load_lds( \
    (const __attribute__((address_space(1))) void*)(g), \
    (__attribute__((address_space(3))) void*)(l), 16, 0, 0)

// ---------------- K0: precompute A_bar, C*B_bar, A_bar^T, log2(A_bar) ----------------
__global__ __launch_bounds__(256) void k_precompute(
    const float* __restrict__ A_log, const float* __restrict__ Bv,
    const float* __restrict__ C, const float* __restrict__ log_dt,
    const float* __restrict__ A_log_r, const float* __restrict__ B_r,
    const float* __restrict__ C_r,
    float* __restrict__ pA, float* __restrict__ pCB, float* __restrict__ pPW,
    float* __restrict__ pLG)
{
    int tid = blockIdx.x * 256 + threadIdx.x;      // 2*512*64
    int n   = tid & 63;
    int h   = (tid >> 6) & 511;
    int dir = tid >> 15;
    float dt = expf(log_dt[h]);
    const float* Al = dir ? A_log_r : A_log;
    const float* Bp = dir ? B_r    : Bv;
    const float* Cp = dir ? C_r    : C;
    float eA = expf(Al[h * N_ST + n]);
    float Ab = expf(-dt * eA);
    float Bb = (1.0f - Ab) / eA * Bp[h * N_ST + n];
    pA[tid]  = Ab;
    pCB[tid] = Cp[h * N_ST + n] * Bb;
    pPW[tid] = expf(-dt * eA * (float)T_CH);
    pLG[tid] = -dt * eA * 1.44269504088896f;       // log2(A_bar)
}

// ---------------- Kw: W_bi f32 -> bf16 ----------------
__global__ __launch_bounds__(256) void k_convw(
    const float* __restrict__ W, __bf16* __restrict__ Wbf)
{
    int tid = blockIdx.x * 256 + threadIdx.x;
    Wbf[tid] = (__bf16)W[tid];
}

// ---------------- k_kk: conv kernel taps kk[dirh][d] = sum_n CB_n A_n^d ----------------
__global__ __launch_bounds__(256) void k_kk(
    const float* __restrict__ pCB, const float* __restrict__ pLG,
    float* __restrict__ kk)
{
    __shared__ float scb[64], slg[64];
    int dirh = blockIdx.x;           // 0..1023
    int d = threadIdx.x;             // 0..255
    if (d < 64) { scb[d] = pCB[dirh * 64 + d]; slg[d] = pLG[dirh * 64 + d]; }
    __syncthreads();
    float s = 0.f;
    #pragma unroll
    for (int n = 0; n < 64; ++n) s += scb[n] * exp2f((float)d * slg[n]);
    kk[dirh * 256 + d] = s;
}

// ---------------- k_ut: u [b,l,h] f32 -> ut [h][b][l] bf16 ----------------
__global__ __launch_bounds__(256) void k_ut(
    const float* __restrict__ u, __bf16* __restrict__ ut)
{
    __shared__ float tl[32][65];
    int blk = blockIdx.x;            // 128 l-tiles * 8 h-tiles * 8 b
    int lt = blk & 127, ht = (blk >> 7) & 7, b = blk >> 10;
    int t = threadIdx.x;
    int ho = t & 63, li = t >> 6;
    #pragma unroll
    for (int it = 0; it < 8; ++it) {
        int l = it * 4 + li;
        tl[l][ho] = u[(size_t)(b * L_SEQ + lt * 32 + l) * H_DIM + ht * 64 + ho];
    }
    __syncthreads();
    int hh = t >> 2, lrun = (t & 3) * 8;
    bf16x8 v;
    #pragma unroll
    for (int i = 0; i < 8; ++i) v[i] = (__bf16)tl[lrun + i][hh];
    *(bf16x8*)(ut + (size_t)(ht * 64 + hh) * 32768 + b * 4096 + lt * 32 + lrun) = v;
}

// ---------------- K1 v2: per-chunk end states via MFMA ----------------
// x_end[dir][n][(b,c)] = sum_j M[dir][n][j] * u[b][c*256+j],
// M_fwd[n][j] = A_n^(255-j), M_rev[n][j] = A_n^j  (computed as exp2(e*log2A)).
// One block per h, 8 waves: wave = (dir, mtile). u-slab staging + swizzled
// B-frag reads identical to k_conv's verified path.
// S2 layout: [dir][h][n>>2][col=b*16+c][n&3] bf16  -> coalesced C-frag stores.
__global__ __launch_bounds__(512, 2) void k_state(
    const __bf16* __restrict__ ut, const float* __restrict__ pLG,
    __bf16* __restrict__ S2)
{
    __shared__ __bf16 uts[16384];   // 32 KB half-slab
    int h = blockIdx.x;
    int t = threadIdx.x;
    int lane = t & 63, w = t >> 6;
    int lr = lane & 15, lg = lane >> 4;
    int dir = w >> 2, mtile = w & 3;

    float s = pLG[(size_t)(dir * 512 + h) * 64 + mtile * 16 + lr];

    // A-frags: Mf[kk] elem jj ~ k = kk*32 + lg*8 + jj
    bf16x8 Mf[8];
    #pragma unroll
    for (int kk = 0; kk < 8; ++kk) {
        #pragma unroll
        for (int jj = 0; jj < 8; ++jj) {
            int j = kk * 32 + lg * 8 + jj;
            float e = dir ? (float)j : (float)(255 - j);
            Mf[kk][jj] = (__bf16)exp2f(e * s);
        }
    }

    for (int hf = 0; hf < 2; ++hf) {
        if (hf) __syncthreads();           // all reads of uts done
        #pragma unroll
        for (int i = 0; i < 4; ++i) {
            int chunk = i * 512 + t;       // 0..2047
            int col   = chunk >> 5;
            int l8    = (chunk & 31) << 3;
            int l8s   = l8 ^ ((col & 7) << 3);
            GLOAD16(ut + (size_t)h * 32768 + (hf * 64 + col) * 256 + l8s,
                    (char*)uts + chunk * 16);
        }
        __syncthreads();

        #pragma unroll
        for (int ntile = 0; ntile < 4; ++ntile) {
            f32x4 acc = {};
            #pragma unroll
            for (int kk = 0; kk < 8; ++kk) {
                int col = ntile * 16 + lr;
                bf16x8 bv = *(const bf16x8*)((char*)uts + col * 512
                             + (((kk * 4 + lg) ^ (col & 7)) << 4));
                acc = __builtin_amdgcn_mfma_f32_16x16x32_bf16(Mf[kk], bv, acc, 0, 0, 0);
            }
            int colg = hf * 64 + ntile * 16 + lr;   // = b*16 + c
            int nq   = mtile * 4 + lg;
            bf16x4 o;
            #pragma unroll
            for (int r = 0; r < 4; ++r) o[r] = (__bf16)acc[r];
            *(bf16x4*)(S2 + ((size_t)((dir * 512 + h) * 16 + nq) * 128 + colg) * 4) = o;
        }
    }
}

// ---------------- K2 v2: inter-chunk scan on S2 (in place) ----------------
// thread = (dir,h,nq,b): owns 128B run (16 chunks x 4 ne), 4 scans in regs.
__global__ __launch_bounds__(256) void k_chunkscan(
    const float* __restrict__ pPW, __bf16* __restrict__ S2)
{
    int tid = blockIdx.x * 256 + threadIdx.x;  // 131072
    int b   = tid & 7;
    int nq  = (tid >> 3) & 15;
    int h   = (tid >> 7) & 511;
    int dir = tid >> 16;
    f32x4 pw4 = *(const f32x4*)(pPW + (size_t)(dir * 512 + h) * 64 + nq * 4);
    __bf16* base = S2 + ((size_t)((dir * 512 + h) * 16 + nq) * 128 + b * 16) * 4;
    bf16x8 v[8];
    #pragma unroll
    for (int i = 0; i < 8; ++i) v[i] = *(const bf16x8*)(base + i * 8);
    float X0 = 0.f, X1 = 0.f, X2 = 0.f, X3 = 0.f;
#define SCAN_STEP(c) do { \
    float t0 = (float)v[(c)>>1][((c)&1)*4+0]; v[(c)>>1][((c)&1)*4+0] = (__bf16)X0; X0 = fmaf(pw4[0], X0, t0); \
    float t1 = (float)v[(c)>>1][((c)&1)*4+1]; v[(c)>>1][((c)&1)*4+1] = (__bf16)X1; X1 = fmaf(pw4[1], X1, t1); \
    float t2 = (float)v[(c)>>1][((c)&1)*4+2]; v[(c)>>1][((c)&1)*4+2] = (__bf16)X2; X2 = fmaf(pw4[2], X2, t2); \
    float t3 = (float)v[(c)>>1][((c)&1)*4+3]; v[(c)>>1][((c)&1)*4+3] = (__bf16)X3; X3 = fmaf(pw4[3], X3, t3); \
    } while (0)
    if (dir == 0) {
        #pragma unroll
        for (int c = 0; c < 16; ++c) SCAN_STEP(c);
    } else {
        #pragma unroll
        for (int c = 15; c >= 0; --c) SCAN_STEP(c);
    }
#undef SCAN_STEP
    #pragma unroll
    for (int i = 0; i < 8; ++i) *(bf16x8*)(base + i * 8) = v[i];
}

// ---------------- k_conv v3: LDS-staged MFMA chunk conv (S2-layout reads) ----------------
template<int DIR>
__device__ __forceinline__ void conv_body(
    int h, int t,
    const float* __restrict__ kk, const float* __restrict__ pLG,
    const float* __restrict__ pCB, const float* __restrict__ Dv,
    const __bf16* __restrict__ ut, const __bf16* __restrict__ S,
    __bf16* __restrict__ ycT,
    __bf16* uts, ull* kkq8, float* slg, float* scb)
{
    int dirh = DIR * 512 + h;
    int lane = t & 63, w = t >> 6;
    int lr = lane & 15, lg = lane >> 4;

    unsigned short* asc = (unsigned short*)uts;
    for (int i = t; i < 548; i += 512) {
        int d = DIR ? (i - 272) : (271 - i);
        float kv = (d >= 0 && d < 256) ? kk[dirh * 256 + d] : 0.f;
        asc[i] = __builtin_bit_cast(unsigned short, (__bf16)kv);
    }
    if (t < 64)       slg[t]      = pLG[dirh * 64 + t];
    else if (t < 128) scb[t - 64] = pCB[dirh * 64 + (t - 64)];
    __syncthreads();
    for (int i = t; i < 544; i += 512)
        kkq8[i] = (ull)asc[i] | ((ull)asc[i+1] << 16) | ((ull)asc[i+2] << 32)
                | ((ull)asc[i+3] << 48);
    __syncthreads();

    float Dh = Dv[h];
    const ull* kq = kkq8;

    for (int hf = 0; hf < 2; ++hf) {
        #pragma unroll
        for (int i = 0; i < 4; ++i) {
            int chunk = i * 512 + t;          // 0..2047
            int col   = chunk >> 5;
            int l8    = (chunk & 31) << 3;
            int l8s   = l8 ^ ((col & 7) << 3);
            GLOAD16(ut + (size_t)h * 32768 + (hf * 64 + col) * 256 + l8s,
                    (char*)uts + chunk * 16);
        }
        __syncthreads();

        f32x4 acc[2][4] = {};

        #pragma unroll
        for (int mf = 0; mf < 2; ++mf) {
            int rt  = mf ? (15 - w) : w;
            int jlo = DIR ? (rt >> 1) : 0;
            int jhi = DIR ? 8 : ((rt >> 1) + 1);
            int sb  = (DIR ? 272 : 271) + lg * 8 - rt * 16 - lr;
            for (int jt = jlo; jt < jhi; ++jt) {
                bf16x8 bv[4];
                #pragma unroll
                for (int n = 0; n < 4; ++n) {
                    int col = n * 16 + lr;
                    bv[n] = *(const bf16x8*)((char*)uts + col * 512
                              + (((jt * 4 + lg) ^ (col & 7)) << 4));
                }
                int si = sb + jt * 32;
                ull lo = kq[si], hi = kq[si + 4];
                bf16x8 av;
                ((ull*)&av)[0] = lo; ((ull*)&av)[1] = hi;
                #pragma unroll
                for (int n = 0; n < 4; ++n)
                    acc[mf][n] = __builtin_amdgcn_mfma_f32_16x16x32_bf16(av, bv[n], acc[mf][n], 0, 0, 0);
            }
        }

        // state injection: S2 layout [dir][h][nq][col][ne]
        #pragma unroll
        for (int nt = 0; nt < 2; ++nt) {
            bf16x8 bs[4];
            #pragma unroll
            for (int n = 0; n < 4; ++n) {
                int colg = (hf * 4 + n) * 16 + lr;       // b*16 + c (c = lr)
                int nq0  = nt * 8 + lg * 2;
                const __bf16* sp = S + ((size_t)((DIR * 512 + h) * 16 + nq0) * 128 + colg) * 4;
                bf16x4 s0 = *(const bf16x4*)(sp);
                bf16x4 s1 = *(const bf16x4*)(sp + 512);
                #pragma unroll
                for (int j = 0; j < 4; ++j) { bs[n][j] = s0[j]; bs[n][4 + j] = s1[j]; }
            }
            #pragma unroll
            for (int mf = 0; mf < 2; ++mf) {
                int rt = mf ? (15 - w) : w;
                int l  = rt * 16 + lr;
                float e = DIR ? (float)(256 - l) : (float)(l + 1);
                bf16x8 gv;
                #pragma unroll
                for (int j = 0; j < 8; ++j) {
                    int n = nt * 32 + lg * 8 + j;
                    gv[j] = (__bf16)(scb[n] * exp2f(e * slg[n]));
                }
                #pragma unroll
                for (int n = 0; n < 4; ++n)
                    acc[mf][n] = __builtin_amdgcn_mfma_f32_16x16x32_bf16(gv, bs[n], acc[mf][n], 0, 0, 0);
            }
        }

        #pragma unroll
        for (int mf = 0; mf < 2; ++mf) {
            int rt = mf ? (15 - w) : w;
            int l0 = rt * 16 + lg * 4;
            #pragma unroll
            for (int n = 0; n < 4; ++n) {
                int col = n * 16 + lr;
                bf16x4 uv = *(const bf16x4*)((char*)uts + col * 512
                             + ((((l0 >> 3) ^ (col & 7)) << 4) | ((l0 & 7) * 2)));
                bf16x4 o;
                #pragma unroll
                for (int r = 0; r < 4; ++r)
                    o[r] = (__bf16)(acc[mf][n][r] + Dh * (float)uv[r]);
                *(bf16x4*)(ycT + (size_t)dirh * 32768 + (hf * 64 + col) * 256 + l0) = o;
            }
        }
        __syncthreads();
    }
}

__global__ __launch_bounds__(512, 4) void k_conv(
    const float* __restrict__ kk, const float* __restrict__ pLG,
    const float* __restrict__ pCB, const float* __restrict__ Dv,
    const __bf16* __restrict__ ut, const __bf16* __restrict__ S,
    __bf16* __restrict__ ycT)
{
    __shared__ __bf16 uts[16384];
    __shared__ ull kkq8[544];
    __shared__ float slg[64], scb[64];
    int h = blockIdx.x & 511;
    int t = threadIdx.x;
    if (blockIdx.x >> 9)
        conv_body<1>(h, t, kk, pLG, pCB, Dv, ut, S, ycT, uts, kkq8, slg, scb);
    else
        conv_body<0>(h, t, kk, pLG, pCB, Dv, ut, S, ycT, uts, kkq8, slg, scb);
}

// ---------------- K4 v6: 2-phase double-buffered GEMM (R11-verified) ----------------
__global__ __launch_bounds__(256, 2) void k_gemm(
    const __bf16* __restrict__ ycT, const __bf16* __restrict__ B,
    const float* __restrict__ bias, float* __restrict__ out)
{
    __shared__ __bf16 As[2][4][128][8];    // 16 KB
    __shared__ __bf16 Bs[2][256][32];      // 32 KB
    int t  = threadIdx.x;
    int l  = t & 63, w = t >> 6;
    int lr = l & 15, lg = l >> 4;
    int mBase = blockIdx.y * 128;
    int nBase = blockIdx.x * 256;
    int wr = (w >> 1) * 64, wc = (w & 1) * 128;

    int sT  = t & 15;           // m-octet
    int skk = t >> 4;           // k 0..15
    int swz = (sT & 7) << 4;

    f32x4 acc[4][8] = {};
    const __bf16* aptr = ycT + mBase + sT * 8;

#define STAGE_A(buf, va0, va1) do { \
    char* AsB_ = (char*)&As[buf][0][0][0]; \
    _Pragma("unroll") \
    for (int p = 0; p < 2; ++p) { \
        int kk_ = skk + p * 16; \
        u16x8 av_ = p ? (va1) : (va0); \
        int kgrp_ = kk_ >> 3, ke_ = kk_ & 7; \
        _Pragma("unroll") \
        for (int i = 0; i < 8; ++i) { \
            int off_ = ((kgrp_ * 128 + sT * 8 + i) * 16 + ke_ * 2) ^ swz; \
            *(unsigned short*)(AsB_ + off_) = av_[i]; \
        } \
    } } while (0)

#define STAGE_B(buf, kt_) do { \
    char* BsB_ = (char*)&Bs[buf][0][0]; \
    _Pragma("unroll") \
    for (int i = 0; i < 4; ++i) { \
        int chunk_ = i * 256 + t; \
        int row_ = chunk_ >> 2, kq_ = chunk_ & 3; \
        int kqs_ = kq_ ^ ((row_ >> 1) & 3); \
        GLOAD16(B + (size_t)(nBase + row_) * K_GEMM + (kt_) + kqs_ * 8, \
                BsB_ + chunk_ * 16); \
    } } while (0)

#define COMPUTE(buf) do { \
    char* AsB_ = (char*)&As[buf][0][0][0]; \
    char* BsB_ = (char*)&Bs[buf][0][0]; \
    bf16x8 af_[4], bfv_[8]; \
    _Pragma("unroll") \
    for (int m = 0; m < 4; ++m) { \
        int row_ = wr + m * 16 + lr; \
        int off_ = ((lg * 128 + row_) * 16) ^ (((row_ >> 3) & 7) << 4); \
        af_[m] = *(const bf16x8*)(AsB_ + off_); \
    } \
    _Pragma("unroll") \
    for (int n = 0; n < 8; ++n) { \
        int row_ = wc + n * 16 + lr; \
        bfv_[n] = *(const bf16x8*)(BsB_ + row_ * 64 \
                    + ((lg * 16) ^ (((row_ >> 1) & 3) << 4))); \
    } \
    _Pragma("unroll") \
    for (int m = 0; m < 4; ++m) \
        _Pragma("unroll") \
        for (int n = 0; n < 8; ++n) \
            acc[m][n] = __builtin_amdgcn_mfma_f32_16x16x32_bf16(af_[m], bfv_[n], acc[m][n], 0, 0, 0); \
    } while (0)

    u16x8 a0 = *(const u16x8*)(aptr + (size_t)skk * 32768);
    u16x8 a1 = *(const u16x8*)(aptr + (size_t)(skk + 16) * 32768);
    STAGE_A(0, a0, a1);
    STAGE_B(0, 0);
    asm volatile("s_waitcnt vmcnt(0)" ::: "memory");
    __builtin_amdgcn_sched_barrier(0);
    a0 = *(const u16x8*)(aptr + (size_t)(32 + skk) * 32768);
    a1 = *(const u16x8*)(aptr + (size_t)(48 + skk) * 32768);
    __builtin_amdgcn_sched_barrier(0);
    asm volatile("s_waitcnt lgkmcnt(0)" ::: "memory");
    __builtin_amdgcn_s_barrier();

    int cur = 0;
    for (int kt = 0; kt < K_GEMM - 32; kt += 32) {
        int nxt = cur ^ 1;
        STAGE_A(nxt, a0, a1);
        STAGE_B(nxt, kt + 32);
        COMPUTE(cur);
        asm volatile("s_waitcnt vmcnt(0)" ::: "memory");
        __builtin_amdgcn_sched_barrier(0);
        if (kt + 64 < K_GEMM) {
            a0 = *(const u16x8*)(aptr + (size_t)(kt + 64 + skk) * 32768);
            a1 = *(const u16x8*)(aptr + (size_t)(kt + 80 + skk) * 32768);
        }
        __builtin_amdgcn_sched_barrier(0);
        asm volatile("s_waitcnt lgkmcnt(0)" ::: "memory");
        __builtin_amdgcn_s_barrier();
        cur = nxt;
    }
    COMPUTE(cur);

#undef STAGE_A
#undef STAGE_B
#undef COMPUTE

    #pragma unroll
    for (int n = 0; n < 8; ++n) {
        int colg = nBase + wc + n * 16 + lr;
        float bv = bias[colg];
        #pragma unroll
        for (int m = 0; m < 4; ++m) {
            int rowg = mBase + wr + m * 16 + lg * 4;
            #pragma unroll
            for (int r = 0; r < 4; ++r)
                out[(size_t)(rowg + r) * H_DIM + colg] = acc[m][n][r] + bv;
        }
    }
}

extern "C" void kernel_launch(void* const* d_in, const int* in_sizes, int n_in,
                              void* d_out, int out_size, void* d_ws, size_t ws_size,
                              hipStream_t stream)
{
    const float* u       = (const float*)d_in[0];
    const float* A_log   = (const float*)d_in[1];
    const float* Bv      = (const float*)d_in[2];
    const float* C       = (const float*)d_in[3];
    const float* D       = (const float*)d_in[4];
    const float* log_dt  = (const float*)d_in[5];
    const float* A_log_r = (const float*)d_in[6];
    const float* B_r     = (const float*)d_in[7];
    const float* C_r     = (const float*)d_in[8];
    const float* W_bi    = (const float*)d_in[9];
    const float* b_bi    = (const float*)d_in[10];
    float* out = (float*)d_out;

    char* ws = (char*)d_ws;
    float* pA   = (float*)(ws + 0x000000);   // 256 KiB
    float* pCB  = (float*)(ws + 0x040000);
    float* pPW  = (float*)(ws + 0x080000);
    float* pLG  = (float*)(ws + 0x0C0000);
    float* kk   = (float*)(ws + 0x100000);   // 1 MiB
    __bf16* Wbf = (__bf16*)(ws + 0x200000);  // 1 MiB
    __bf16* S   = (__bf16*)(ws + 0x300000);  // 16 MiB (S2 layout)
    __bf16* ut  = (__bf16*)(ws + 0x1300000); // 32 MiB
    __bf16* ycT = (__bf16*)(ws + 0x3300000); // 64 MiB  (end 115 MiB)

    k_precompute<<<256,  256, 0, stream>>>(A_log, Bv, C, log_dt, A_log_r, B_r, C_r,
                                           pA, pCB, pPW, pLG);
    k_convw     <<<2048, 256, 0, stream>>>(W_bi, Wbf);
    k_kk        <<<1024, 256, 0, stream>>>(pCB, pLG, kk);
    k_ut        <<<8192, 256, 0, stream>>>(u, ut);
    k_state     <<<512,  512, 0, stream>>>(ut, pLG, S);
    k_chunkscan <<<512,  256, 0, stream>>>(pPW, S);
    k_conv      <<<1024, 512, 0, stream>>>(kk, pLG, pCB, D, ut, S, ycT);
    dim3 g(2, 256);
    k_gemm      <<<g,    256, 0, stream>>>(ycT, Wbf, b_bi, out);
}

// Round 13
// 137.717 us; speedup vs baseline: 2.3546x; 1.0676x over previous
//
#include <hip/hip_runtime.h>
#include <hip/hip_bf16.h>
#include <stdint.h>

#define L_SEQ  4096
#define H_DIM  512
#define N_ST   64
#define N_B    8
#define N_CH   16
#define T_CH   256
#define K_GEMM 1024

typedef float  f32x4  __attribute__((ext_vector_type(4)));
typedef __bf16 bf16x8 __attribute__((ext_vector_type(8)));
typedef __bf16 bf16x4 __attribute__((ext_vector_type(4)));
typedef unsigned short u16x8 __attribute__((ext_vector_type(8)));
typedef unsigned long long ull;

#define GLOAD16(g, l) __builtin_amdgcn_global_load_lds( \
    (const __attribute__((address_space(1))) void*)(g), \
    (__attribute__((address_space(3))) void*)(l), 16, 0, 0)

// ---------------- k_kk: per-(dir,h) params + conv kernel taps ----------------
// Fuses old k_precompute: block dirh computes its own 64 params, publishes
// pLG/pCB/pPW for downstream kernels, then computes taps kk[dirh][d].
__global__ __launch_bounds__(256) void k_kk(
    const float* __restrict__ A_log, const float* __restrict__ Bv,
    const float* __restrict__ C, const float* __restrict__ log_dt,
    const float* __restrict__ A_log_r, const float* __restrict__ B_r,
    const float* __restrict__ C_r,
    float* __restrict__ kk, float* __restrict__ pLG,
    float* __restrict__ pCB, float* __restrict__ pPW)
{
    __shared__ float scb[64], slg[64];
    int dirh = blockIdx.x;           // 0..1023
    int dir  = dirh >> 9, h = dirh & 511;
    int d = threadIdx.x;             // 0..255
    if (d < 64) {
        int n = d;
        float dt = expf(log_dt[h]);
        const float* Al = dir ? A_log_r : A_log;
        const float* Bp = dir ? B_r    : Bv;
        const float* Cp = dir ? C_r    : C;
        float eA = expf(Al[h * N_ST + n]);
        float Ab = expf(-dt * eA);
        float Bb = (1.0f - Ab) / eA * Bp[h * N_ST + n];
        float cb = Cp[h * N_ST + n] * Bb;
        float lg = -dt * eA * 1.44269504088896f;
        scb[n] = cb; slg[n] = lg;
        pCB[dirh * 64 + n] = cb;
        pLG[dirh * 64 + n] = lg;
        pPW[dirh * 64 + n] = expf(-dt * eA * (float)T_CH);
    }
    __syncthreads();
    float s = 0.f;
    #pragma unroll
    for (int n = 0; n < 64; ++n) s += scb[n] * exp2f((float)d * slg[n]);
    kk[dirh * 256 + d] = s;
}

// ---------------- k_ut: u [b,l,h] f32 -> ut [h][b][l] bf16 (+ W->bf16 tail) ----------------
__global__ __launch_bounds__(256) void k_ut(
    const float* __restrict__ u, __bf16* __restrict__ ut,
    const float* __restrict__ W, __bf16* __restrict__ Wbf)
{
    __shared__ float tl[32][65];
    int blk = blockIdx.x;            // 128 l-tiles * 8 h-tiles * 8 b
    int lt = blk & 127, ht = (blk >> 7) & 7, b = blk >> 10;
    int t = threadIdx.x;
    int ho = t & 63, li = t >> 6;
    #pragma unroll
    for (int it = 0; it < 8; ++it) {
        int l = it * 4 + li;
        tl[l][ho] = u[(size_t)(b * L_SEQ + lt * 32 + l) * H_DIM + ht * 64 + ho];
    }
    if (blk < 2048) {                 // fused W f32->bf16 (512*1024 = 2048*256)
        int i = blk * 256 + t;
        Wbf[i] = (__bf16)W[i];
    }
    __syncthreads();
    int hh = t >> 2, lrun = (t & 3) * 8;
    bf16x8 v;
    #pragma unroll
    for (int i = 0; i < 8; ++i) v[i] = (__bf16)tl[lrun + i][hh];
    *(bf16x8*)(ut + (size_t)(ht * 64 + hh) * 32768 + b * 4096 + lt * 32 + lrun) = v;
}

// ---------------- K1 v3: per-chunk end states via MFMA + fused inter-chunk scan ----------------
// acc C-frag: col = b*16+c with c = lr, row n = mtile*16+lg*4+r. The 16 chunks
// of a scan group live in the 16 lr-lanes -> cross-lane affine prefix scan
// (Hillis-Steele, multiplier pw = A_bar^256) replaces the k_chunkscan kernel.
// S2 written ALREADY SCANNED (incoming state for each chunk).
__global__ __launch_bounds__(512, 2) void k_state(
    const __bf16* __restrict__ ut, const float* __restrict__ pLG,
    const float* __restrict__ pPW, __bf16* __restrict__ S2)
{
    __shared__ __bf16 uts[16384];   // 32 KB half-slab
    int h = blockIdx.x;
    int t = threadIdx.x;
    int lane = t & 63, w = t >> 6;
    int lr = lane & 15, lg = lane >> 4;
    int dir = w >> 2, mtile = w & 3;

    float s = pLG[(size_t)(dir * 512 + h) * 64 + mtile * 16 + lr];
    f32x4 pw4 = *(const f32x4*)(pPW + (size_t)(dir * 512 + h) * 64 + mtile * 16 + lg * 4);

    bf16x8 Mf[8];
    #pragma unroll
    for (int kk = 0; kk < 8; ++kk) {
        #pragma unroll
        for (int jj = 0; jj < 8; ++jj) {
            int j = kk * 32 + lg * 8 + jj;
            float e = dir ? (float)j : (float)(255 - j);
            Mf[kk][jj] = (__bf16)exp2f(e * s);
        }
    }

    for (int hf = 0; hf < 2; ++hf) {
        if (hf) __syncthreads();
        #pragma unroll
        for (int i = 0; i < 4; ++i) {
            int chunk = i * 512 + t;       // 0..2047
            int col   = chunk >> 5;
            int l8    = (chunk & 31) << 3;
            int l8s   = l8 ^ ((col & 7) << 3);
            GLOAD16(ut + (size_t)h * 32768 + (hf * 64 + col) * 256 + l8s,
                    (char*)uts + chunk * 16);
        }
        __syncthreads();

        #pragma unroll
        for (int ntile = 0; ntile < 4; ++ntile) {
            f32x4 acc = {};
            #pragma unroll
            for (int kk = 0; kk < 8; ++kk) {
                int col = ntile * 16 + lr;
                bf16x8 bv = *(const bf16x8*)((char*)uts + col * 512
                             + (((kk * 4 + lg) ^ (col & 7)) << 4));
                acc = __builtin_amdgcn_mfma_f32_16x16x32_bf16(Mf[kk], bv, acc, 0, 0, 0);
            }
            // ---- fused affine prefix scan across lr (= chunk c) ----
            f32x4 X;
            if (dir == 0) {
                f32x4 incl = acc;
                float p0 = pw4[0], p1 = pw4[1], p2 = pw4[2], p3 = pw4[3];
                #pragma unroll
                for (int st = 1; st <= 8; st <<= 1) {
                    float u0 = __shfl(incl[0], (lane - st) & 63);
                    float u1 = __shfl(incl[1], (lane - st) & 63);
                    float u2 = __shfl(incl[2], (lane - st) & 63);
                    float u3 = __shfl(incl[3], (lane - st) & 63);
                    if (lr >= st) {
                        incl[0] = fmaf(p0, u0, incl[0]);
                        incl[1] = fmaf(p1, u1, incl[1]);
                        incl[2] = fmaf(p2, u2, incl[2]);
                        incl[3] = fmaf(p3, u3, incl[3]);
                    }
                    p0 *= p0; p1 *= p1; p2 *= p2; p3 *= p3;
                }
                #pragma unroll
                for (int r = 0; r < 4; ++r) {
                    float sh = __shfl(incl[r], (lane - 1) & 63);
                    X[r] = (lr == 0) ? 0.f : sh;
                }
            } else {
                f32x4 incl = acc;
                float p0 = pw4[0], p1 = pw4[1], p2 = pw4[2], p3 = pw4[3];
                #pragma unroll
                for (int st = 1; st <= 8; st <<= 1) {
                    float u0 = __shfl(incl[0], (lane + st) & 63);
                    float u1 = __shfl(incl[1], (lane + st) & 63);
                    float u2 = __shfl(incl[2], (lane + st) & 63);
                    float u3 = __shfl(incl[3], (lane + st) & 63);
                    if (lr <= 15 - st) {
                        incl[0] = fmaf(p0, u0, incl[0]);
                        incl[1] = fmaf(p1, u1, incl[1]);
                        incl[2] = fmaf(p2, u2, incl[2]);
                        incl[3] = fmaf(p3, u3, incl[3]);
                    }
                    p0 *= p0; p1 *= p1; p2 *= p2; p3 *= p3;
                }
                #pragma unroll
                for (int r = 0; r < 4; ++r) {
                    float sh = __shfl(incl[r], (lane + 1) & 63);
                    X[r] = (lr == 15) ? 0.f : sh;
                }
            }
            int colg = hf * 64 + ntile * 16 + lr;   // = b*16 + c
            int nq   = mtile * 4 + lg;
            bf16x4 o;
            #pragma unroll
            for (int r = 0; r < 4; ++r) o[r] = (__bf16)X[r];
            *(bf16x4*)(S2 + ((size_t)((dir * 512 + h) * 16 + nq) * 128 + colg) * 4) = o;
        }
    }
}

// ---------------- k_conv: LDS-staged MFMA chunk conv (G-frags hoisted) ----------------
template<int DIR>
__device__ __forceinline__ void conv_body(
    int h, int t,
    const float* __restrict__ kk, const float* __restrict__ pLG,
    const float* __restrict__ pCB, const float* __restrict__ Dv,
    const __bf16* __restrict__ ut, const __bf16* __restrict__ S,
    __bf16* __restrict__ ycT,
    __bf16* uts, ull* kkq8, float* slg, float* scb)
{
    int dirh = DIR * 512 + h;
    int lane = t & 63, w = t >> 6;
    int lr = lane & 15, lg = lane >> 4;

    unsigned short* asc = (unsigned short*)uts;
    for (int i = t; i < 548; i += 512) {
        int d = DIR ? (i - 272) : (271 - i);
        float kv = (d >= 0 && d < 256) ? kk[dirh * 256 + d] : 0.f;
        asc[i] = __builtin_bit_cast(unsigned short, (__bf16)kv);
    }
    if (t < 64)       slg[t]      = pLG[dirh * 64 + t];
    else if (t < 128) scb[t - 64] = pCB[dirh * 64 + (t - 64)];
    __syncthreads();
    for (int i = t; i < 544; i += 512)
        kkq8[i] = (ull)asc[i] | ((ull)asc[i+1] << 16) | ((ull)asc[i+2] << 32)
                | ((ull)asc[i+3] << 48);
    __syncthreads();

    // hoisted G-fragments (hf-invariant)
    bf16x8 gvv[2][2];
    #pragma unroll
    for (int nt = 0; nt < 2; ++nt)
        #pragma unroll
        for (int mf = 0; mf < 2; ++mf) {
            int rt = mf ? (15 - w) : w;
            int l  = rt * 16 + lr;
            float e = DIR ? (float)(256 - l) : (float)(l + 1);
            #pragma unroll
            for (int j = 0; j < 8; ++j) {
                int n = nt * 32 + lg * 8 + j;
                gvv[nt][mf][j] = (__bf16)(scb[n] * exp2f(e * slg[n]));
            }
        }

    float Dh = Dv[h];
    const ull* kq = kkq8;

    for (int hf = 0; hf < 2; ++hf) {
        #pragma unroll
        for (int i = 0; i < 4; ++i) {
            int chunk = i * 512 + t;          // 0..2047
            int col   = chunk >> 5;
            int l8    = (chunk & 31) << 3;
            int l8s   = l8 ^ ((col & 7) << 3);
            GLOAD16(ut + (size_t)h * 32768 + (hf * 64 + col) * 256 + l8s,
                    (char*)uts + chunk * 16);
        }
        __syncthreads();

        f32x4 acc[2][4] = {};

        #pragma unroll
        for (int mf = 0; mf < 2; ++mf) {
            int rt  = mf ? (15 - w) : w;
            int jlo = DIR ? (rt >> 1) : 0;
            int jhi = DIR ? 8 : ((rt >> 1) + 1);
            int sb  = (DIR ? 272 : 271) + lg * 8 - rt * 16 - lr;
            for (int jt = jlo; jt < jhi; ++jt) {
                bf16x8 bv[4];
                #pragma unroll
                for (int n = 0; n < 4; ++n) {
                    int col = n * 16 + lr;
                    bv[n] = *(const bf16x8*)((char*)uts + col * 512
                              + (((jt * 4 + lg) ^ (col & 7)) << 4));
                }
                int si = sb + jt * 32;
                ull lo = kq[si], hi = kq[si + 4];
                bf16x8 av;
                ((ull*)&av)[0] = lo; ((ull*)&av)[1] = hi;
                #pragma unroll
                for (int n = 0; n < 4; ++n)
                    acc[mf][n] = __builtin_amdgcn_mfma_f32_16x16x32_bf16(av, bv[n], acc[mf][n], 0, 0, 0);
            }
        }

        // state injection: S2 layout [dir][h][nq][col][ne]
        #pragma unroll
        for (int nt = 0; nt < 2; ++nt) {
            bf16x8 bs[4];
            #pragma unroll
            for (int n = 0; n < 4; ++n) {
                int colg = (hf * 4 + n) * 16 + lr;
                int nq0  = nt * 8 + lg * 2;
                const __bf16* sp = S + ((size_t)((DIR * 512 + h) * 16 + nq0) * 128 + colg) * 4;
                bf16x4 s0 = *(const bf16x4*)(sp);
                bf16x4 s1 = *(const bf16x4*)(sp + 512);
                #pragma unroll
                for (int j = 0; j < 4; ++j) { bs[n][j] = s0[j]; bs[n][4 + j] = s1[j]; }
            }
            #pragma unroll
            for (int mf = 0; mf < 2; ++mf)
                #pragma unroll
                for (int n = 0; n < 4; ++n)
                    acc[mf][n] = __builtin_amdgcn_mfma_f32_16x16x32_bf16(gvv[nt][mf], bs[n], acc[mf][n], 0, 0, 0);
        }

        #pragma unroll
        for (int mf = 0; mf < 2; ++mf) {
            int rt = mf ? (15 - w) : w;
            int l0 = rt * 16 + lg * 4;
            #pragma unroll
            for (int n = 0; n < 4; ++n) {
                int col = n * 16 + lr;
                bf16x4 uv = *(const bf16x4*)((char*)uts + col * 512
                             + ((((l0 >> 3) ^ (col & 7)) << 4) | ((l0 & 7) * 2)));
                bf16x4 o;
                #pragma unroll
                for (int r = 0; r < 4; ++r)
                    o[r] = (__bf16)(acc[mf][n][r] + Dh * (float)uv[r]);
                *(bf16x4*)(ycT + (size_t)dirh * 32768 + (hf * 64 + col) * 256 + l0) = o;
            }
        }
        __syncthreads();
    }
}

__global__ __launch_bounds__(512, 4) void k_conv(
    const float* __restrict__ kk, const float* __restrict__ pLG,
    const float* __restrict__ pCB, const float* __restrict__ Dv,
    const __bf16* __restrict__ ut, const __bf16* __restrict__ S,
    __bf16* __restrict__ ycT)
{
    __shared__ __bf16 uts[16384];
    __shared__ ull kkq8[544];
    __shared__ float slg[64], scb[64];
    int h = blockIdx.x & 511;
    int t = threadIdx.x;
    if (blockIdx.x >> 9)
        conv_body<1>(h, t, kk, pLG, pCB, Dv, ut, S, ycT, uts, kkq8, slg, scb);
    else
        conv_body<0>(h, t, kk, pLG, pCB, Dv, ut, S, ycT, uts, kkq8, slg, scb);
}

// ---------------- K4 v7: 2-phase dbuf GEMM, paired-u32 A-staging ----------------
__global__ __launch_bounds__(256, 2) void k_gemm(
    const __bf16* __restrict__ ycT, const __bf16* __restrict__ B,
    const float* __restrict__ bias, float* __restrict__ out)
{
    __shared__ __bf16 As[2][4][128][8];    // 16 KB
    __shared__ __bf16 Bs[2][256][32];      // 32 KB
    int t  = threadIdx.x;
    int l  = t & 63, w = t >> 6;
    int lr = l & 15, lg = l >> 4;
    int mBase = blockIdx.y * 128;
    int nBase = blockIdx.x * 256;
    int wr = (w >> 1) * 64, wc = (w & 1) * 128;

    int sT  = t & 15;           // m-octet
    int sp  = t >> 4;           // k-pair 0..15 (k = 2sp, 2sp+1)
    int swz  = (sT & 7) << 4;
    int kgrp = sp >> 2;
    int keb  = (sp & 3) * 4;    // byte offset of the u32 within the 16B row

    f32x4 acc[4][8] = {};
    const __bf16* aptr = ycT + mBase + sT * 8;

#define STAGE_A(buf, va0, va1) do { \
    char* AsB_ = (char*)&As[buf][0][0][0]; \
    _Pragma("unroll") \
    for (int i = 0; i < 8; ++i) { \
        unsigned v_ = (unsigned)(unsigned short)(va0)[i] \
                    | ((unsigned)(unsigned short)(va1)[i] << 16); \
        int off_ = ((kgrp * 128 + sT * 8 + i) * 16 + keb) ^ swz; \
        *(unsigned*)(AsB_ + off_) = v_; \
    } } while (0)

#define STAGE_B(buf, kt_) do { \
    char* BsB_ = (char*)&Bs[buf][0][0]; \
    _Pragma("unroll") \
    for (int i = 0; i < 4; ++i) { \
        int chunk_ = i * 256 + t; \
        int row_ = chunk_ >> 2, kq_ = chunk_ & 3; \
        int kqs_ = kq_ ^ ((row_ >> 1) & 3); \
        GLOAD16(B + (size_t)(nBase + row_) * K_GEMM + (kt_) + kqs_ * 8, \
                BsB_ + chunk_ * 16); \
    } } while (0)

#define COMPUTE(buf) do { \
    char* AsB_ = (char*)&As[buf][0][0][0]; \
    char* BsB_ = (char*)&Bs[buf][0][0]; \
    bf16x8 af_[4], bfv_[8]; \
    _Pragma("unroll") \
    for (int m = 0; m < 4; ++m) { \
        int row_ = wr + m * 16 + lr; \
        int off_ = ((lg * 128 + row_) * 16) ^ (((row_ >> 3) & 7) << 4); \
        af_[m] = *(const bf16x8*)(AsB_ + off_); \
    } \
    _Pragma("unroll") \
    for (int n = 0; n < 8; ++n) { \
        int row_ = wc + n * 16 + lr; \
        bfv_[n] = *(const bf16x8*)(BsB_ + row_ * 64 \
                    + ((lg * 16) ^ (((row_ >> 1) & 3) << 4))); \
    } \
    _Pragma("unroll") \
    for (int m = 0; m < 4; ++m) \
        _Pragma("unroll") \
        for (int n = 0; n < 8; ++n) \
            acc[m][n] = __builtin_amdgcn_mfma_f32_16x16x32_bf16(af_[m], bfv_[n], acc[m][n], 0, 0, 0); \
    } while (0)

    u16x8 a0 = *(const u16x8*)(aptr + (size_t)(2 * sp) * 32768);
    u16x8 a1 = *(const u16x8*)(aptr + (size_t)(2 * sp + 1) * 32768);
    STAGE_A(0, a0, a1);
    STAGE_B(0, 0);
    asm volatile("s_waitcnt vmcnt(0)" ::: "memory");
    __builtin_amdgcn_sched_barrier(0);
    a0 = *(const u16x8*)(aptr + (size_t)(32 + 2 * sp) * 32768);
    a1 = *(const u16x8*)(aptr + (size_t)(32 + 2 * sp + 1) * 32768);
    __builtin_amdgcn_sched_barrier(0);
    asm volatile("s_waitcnt lgkmcnt(0)" ::: "memory");
    __builtin_amdgcn_s_barrier();

    int cur = 0;
    for (int kt = 0; kt < K_GEMM - 32; kt += 32) {
        int nxt = cur ^ 1;
        STAGE_A(nxt, a0, a1);
        STAGE_B(nxt, kt + 32);
        COMPUTE(cur);
        asm volatile("s_waitcnt vmcnt(0)" ::: "memory");
        __builtin_amdgcn_sched_barrier(0);
        if (kt + 64 < K_GEMM) {
            a0 = *(const u16x8*)(aptr + (size_t)(kt + 64 + 2 * sp) * 32768);
            a1 = *(const u16x8*)(aptr + (size_t)(kt + 64 + 2 * sp + 1) * 32768);
        }
        __builtin_amdgcn_sched_barrier(0);
        asm volatile("s_waitcnt lgkmcnt(0)" ::: "memory");
        __builtin_amdgcn_s_barrier();
        cur = nxt;
    }
    COMPUTE(cur);

#undef STAGE_A
#undef STAGE_B
#undef COMPUTE

    #pragma unroll
    for (int n = 0; n < 8; ++n) {
        int colg = nBase + wc + n * 16 + lr;
        float bv = bias[colg];
        #pragma unroll
        for (int m = 0; m < 4; ++m) {
            int rowg = mBase + wr + m * 16 + lg * 4;
            #pragma unroll
            for (int r = 0; r < 4; ++r)
                out[(size_t)(rowg + r) * H_DIM + colg] = acc[m][n][r] + bv;
        }
    }
}

extern "C" void kernel_launch(void* const* d_in, const int* in_sizes, int n_in,
                              void* d_out, int out_size, void* d_ws, size_t ws_size,
                              hipStream_t stream)
{
    const float* u       = (const float*)d_in[0];
    const float* A_log   = (const float*)d_in[1];
    const float* Bv      = (const float*)d_in[2];
    const float* C       = (const float*)d_in[3];
    const float* D       = (const float*)d_in[4];
    const float* log_dt  = (const float*)d_in[5];
    const float* A_log_r = (const float*)d_in[6];
    const float* B_r     = (const float*)d_in[7];
    const float* C_r     = (const float*)d_in[8];
    const float* W_bi    = (const float*)d_in[9];
    const float* b_bi    = (const float*)d_in[10];
    float* out = (float*)d_out;

    char* ws = (char*)d_ws;
    float* pCB  = (float*)(ws + 0x040000);
    float* pPW  = (float*)(ws + 0x080000);
    float* pLG  = (float*)(ws + 0x0C0000);
    float* kk   = (float*)(ws + 0x100000);   // 1 MiB
    __bf16* Wbf = (__bf16*)(ws + 0x200000);  // 1 MiB
    __bf16* S   = (__bf16*)(ws + 0x300000);  // 16 MiB (S2 layout, scanned)
    __bf16* ut  = (__bf16*)(ws + 0x1300000); // 32 MiB
    __bf16* ycT = (__bf16*)(ws + 0x3300000); // 64 MiB  (end 115 MiB)

    k_kk   <<<1024, 256, 0, stream>>>(A_log, Bv, C, log_dt, A_log_r, B_r, C_r,
                                      kk, pLG, pCB, pPW);
    k_ut   <<<8192, 256, 0, stream>>>(u, ut, W_bi, Wbf);
    k_state<<<512,  512, 0, stream>>>(ut, pLG, pPW, S);
    k_conv <<<1024, 512, 0, stream>>>(kk, pLG, pCB, D, ut, S, ycT);
    dim3 g(2, 256);
    k_gemm <<<g,    256, 0, stream>>>(ycT, Wbf, b_bi, out);
}